// Round 11
// baseline (755.121 us; speedup 1.0000x reference)
//
#include <hip/hip_runtime.h>

#define CNUM 1024
#define CDIM 256
#define EPS_CAND 6.0f

// out region offsets in FP32 elements (zbar, zsoft, zhard, symbols, phisoft)
#define OFF_ZBAR   ((size_t)0)
#define OFF_ZSOFT  ((size_t)16777216)
#define OFF_ZHARD  ((size_t)33554432)
#define OFF_SYM    ((size_t)50331648)
#define OFF_PHI    ((size_t)50397184)

typedef __attribute__((ext_vector_type(8))) short bf16x8;
typedef __attribute__((ext_vector_type(4))) float f32x4;
typedef __attribute__((ext_vector_type(4))) unsigned short u16x4;

__device__ __forceinline__ unsigned short f2bf(float f){
  unsigned u = __float_as_uint(f);
  u += 0x7fffu + ((u >> 16) & 1u);
  return (unsigned short)(u >> 16);
}
__device__ __forceinline__ float bf2f(unsigned short h){
  return __uint_as_float(((unsigned)h) << 16);
}
__device__ __forceinline__ float clamp01(float v){ return fminf(1.0f, fmaxf(0.0f, v)); }
__device__ __forceinline__ float dot4(float4 a, float4 b){ return a.x*b.x + a.y*b.y + a.z*b.z + a.w*b.w; }

// ---------- prep: centers fp32 -> bf16 row-major (cb16) + transposed (ct16) ----------
__global__ __launch_bounds__(256) void prep_convert(const float* __restrict__ centers,
                                                    unsigned short* __restrict__ cb16,
                                                    unsigned short* __restrict__ ct16){
  int gid = blockIdx.x*256 + threadIdx.x;        // 65536 = 1024 c x 64 quads
  int c = gid >> 6, d0 = (gid & 63)*4;
  float4 v = *reinterpret_cast<const float4*>(centers + (size_t)c*CDIM + d0);
  unsigned short b0=f2bf(v.x), b1=f2bf(v.y), b2=f2bf(v.z), b3=f2bf(v.w);
  unsigned lo = (unsigned)b0 | ((unsigned)b1<<16);
  unsigned hi = (unsigned)b2 | ((unsigned)b3<<16);
  *reinterpret_cast<uint2*>(cb16 + (size_t)c*CDIM + d0) = make_uint2(lo, hi);
  ct16[(size_t)(d0+0)*CNUM + c] = b0;
  ct16[(size_t)(d0+1)*CNUM + c] = b1;
  ct16[(size_t)(d0+2)*CNUM + c] = b2;
  ct16[(size_t)(d0+3)*CNUM + c] = b3;
}

__global__ __launch_bounds__(256) void prep_e2(const float* __restrict__ centers, float* __restrict__ e2){
  int k = blockIdx.x*256 + threadIdx.x;          // 1024
  const float4* c4 = reinterpret_cast<const float4*>(centers) + (size_t)k*(CDIM/4);
  float s = 0.f;
  #pragma unroll
  for (int i=0;i<CDIM/4;i++){ float4 v = c4[i]; s += dot4(v,v); }
  e2[k] = s;
}

// ---------- K1: GEMM1 (MFMA bf16), writes s' = e2 - 2*x.e (fp32) into phisoft region ----------
// block = 64 tokens; grid 1024 XCD-swizzled. R7-proven structure.
__global__ __launch_bounds__(512) void k1_gemm1(const float* __restrict__ data,
                                                const unsigned short* __restrict__ cb16,
                                                const float* __restrict__ e2g,
                                                float* __restrict__ sqo){
  __shared__ unsigned short xb[64*256];   // [t][swizzled d-slot], row=512B
  __shared__ unsigned short cb[64*256];   // [c][swizzled d-slot], 64-center chunk
  __shared__ float e2s[64];

  const int tid = threadIdx.x;
  const int w = tid>>6, lane = tid&63;
  const int l15 = lane&15, g = lane>>4;
  const int sb = (blockIdx.x & 7)*128 + (blockIdx.x >> 3);
  const int b = sb>>4, hw0 = (sb&15)*64;

  // stage x: wave w owns d in [32w,32w+32); lane = token
  {
    const float* dp = data + ((size_t)b*CDIM + 32*w)*1024 + hw0 + lane;
    #pragma unroll
    for (int i=0;i<16;i++){
      int dd = 2*i;
      float v0 = dp[(size_t)dd*1024];
      float v1 = dp[(size_t)(dd+1)*1024];
      unsigned pk = (unsigned)f2bf(v0) | ((unsigned)f2bf(v1)<<16);
      int d = 32*w + dd;
      int s = d>>3;
      *reinterpret_cast<unsigned*>((char*)xb + lane*512 + (((s ^ (lane&7))<<4)) + (d&7)*2) = pk;
    }
  }

  const int tt  = w & 3;     // token tile (16 tokens)
  const int ch2 = w >> 2;    // 0/1 -> centers 32*ch2 .. +32 within chunk

  for (int cc=0; cc<16; cc++){
    __syncthreads();
    #pragma unroll
    for (int it=0; it<4; it++){
      int e = tid + 512*it;           // 0..2047 : c = e>>5, s = e&31
      int c = e>>5, s = e&31;
      uint4 v = *reinterpret_cast<const uint4*>(cb16 + ((size_t)(cc*64 + c))*CDIM + s*8);
      *reinterpret_cast<uint4*>((char*)cb + c*512 + ((s ^ (c&7))<<4)) = v;
    }
    if (tid < 64) e2s[tid] = e2g[cc*64 + tid];
    __syncthreads();

    f32x4 acc0 = {0.f,0.f,0.f,0.f}, acc1 = {0.f,0.f,0.f,0.f};
    const int t = 16*tt + l15;
    const int c0 = 32*ch2 + l15, c1 = c0 + 16;
    #pragma unroll
    for (int k=0;k<8;k++){
      bf16x8 bf = *reinterpret_cast<const bf16x8*>((const char*)xb + t*512 + (((4*k+g) ^ (t&7))<<4));
      bf16x8 a0 = *reinterpret_cast<const bf16x8*>((const char*)cb + c0*512 + (((4*k+g) ^ (c0&7))<<4));
      bf16x8 a1 = *reinterpret_cast<const bf16x8*>((const char*)cb + c1*512 + (((4*k+g) ^ (c1&7))<<4));
      acc0 = __builtin_amdgcn_mfma_f32_16x16x32_bf16(a0, bf, acc0, 0,0,0);
      acc1 = __builtin_amdgcn_mfma_f32_16x16x32_bf16(a1, bf, acc1, 0,0,0);
    }
    size_t outbase = (size_t)b*1048576 + (size_t)hw0 + 16*tt + l15;
    #pragma unroll
    for (int r=0;r<4;r++){
      int cr0 = 32*ch2 + 4*g + r;
      int cr1 = cr0 + 16;
      sqo[outbase + (size_t)(cc*64 + cr0)*1024] = e2s[cr0] - 2.0f*acc0[r];
      sqo[outbase + (size_t)(cc*64 + cr1)*1024] = e2s[cr1] - 2.0f*acc1[r];
    }
  }
}

// ---------- K2: softmax + exact argmin + phi/sym/zbar/zhard + GEMM2(zsoft) ----------
// 32 tokens/block, 512 threads, grid 2048 XCD-swizzled. LDS 80 KB -> 2 blocks/CU.
__global__ __launch_bounds__(512, 4) void k2_all(const float* __restrict__ data,
                                                 const float* __restrict__ centers,
                                                 const unsigned short* __restrict__ ct16,
                                                 float* __restrict__ out)
{
  __shared__ unsigned short S[32*1024];  // 64 KB: s' bf16 -> phi bf16, rows 2048B, swz (t&15)<<4
  __shared__ unsigned short H[32*256];   // 16 KB: hard bf16 -> zsoft bf16, rows 512B, swz

  const int tid = threadIdx.x;
  const int w = tid>>6, lane = tid&63;
  const int l15 = lane&15, g = lane>>4;
  const int sb = (blockIdx.x & 7)*256 + (blockIdx.x >> 3);
  const int tok0 = sb*32;
  const int bb = tok0>>10, hw0 = tok0&1023;
  float* sqg = out + OFF_PHI;

  // ---- P0: stage s' fp32 [c][1024hw] -> S bf16 [t][c] (transposed, swizzled) ----
  #pragma unroll
  for (int it=0; it<16; ++it){
    int e = tid + 512*it;                // 0..8191: c = e>>3, q = e&7 (token-quad)
    int c = e>>3, q = e&7;
    float4 v = *reinterpret_cast<const float4*>(sqg + (size_t)bb*1048576 + (size_t)c*1024 + hw0 + 4*q);
    const float* vp = (const float*)&v;
    #pragma unroll
    for (int u=0;u<4;u++){
      int t = 4*q + u;
      *(unsigned short*)((char*)S + (size_t)t*2048 + ((2*c) ^ ((t&15)<<4))) = f2bf(vp[u]);
    }
  }
  __syncthreads();

  // ---- P1: per-token softmax + fp64-refined argmin (two passes of 16 tokens) ----
  for (int p=0;p<2;p++){
    const int t = p*16 + (tid>>5);
    const int j = tid&31;
    const int hb = (lane>=32)?32:0;
    const int tswz = (t&15)<<4;
    char* srow = (char*)S + (size_t)t*2048;

    float x2 = 0.f;
    const float* xp = data + (size_t)bb*262144 + hw0 + t;
    #pragma unroll
    for (int q2=0;q2<8;q2++){ float f = xp[(size_t)(j+32*q2)*1024]; x2 += f*f; }
    #pragma unroll
    for (int m=16;m>=1;m>>=1) x2 += __shfl_xor(x2, m);

    float a[32];
    float mns = 3.4e38f;
    #pragma unroll
    for (int i=0;i<32;i++){
      float sp = bf2f(*(const unsigned short*)(srow + ((2*(j+32*i)) ^ tswz)));
      a[i] = sp;
      mns = fminf(mns, sp);
    }
    #pragma unroll
    for (int m=16;m>=1;m>>=1) mns = fminf(mns, __shfl_xor(mns, m));
    float thr = mns + EPS_CAND;
    unsigned cm = 0;
    #pragma unroll
    for (int i=0;i<32;i++) if (a[i] < thr) cm |= (1u<<i);

    double bestd = 1.0e300; int bestk = CNUM;
    for(;;){
      unsigned long long bal = __ballot(cm != 0);
      unsigned half = (lane<32)? (unsigned)(bal & 0xffffffffULL) : (unsigned)(bal>>32);
      if (!half) break;
      int src = __ffs(half)-1;
      unsigned cmsrc = (unsigned)__shfl((int)cm, hb + src);
      int ii = __ffs(cmsrc)-1;
      int k = src + 32*ii;
      if (j==src) cm &= ~(1u<<ii);
      double acc = 0.0;
      const float* crow = centers + (size_t)k*CDIM;
      #pragma unroll
      for (int q2=0;q2<8;q2++){
        double xv = (double)xp[(size_t)(j+32*q2)*1024];
        double ev = (double)crow[j+32*q2];
        double df = xv-ev; acc = fma(df,df,acc);
      }
      #pragma unroll
      for (int m=16;m>=1;m>>=1) acc += __shfl_xor(acc, m);
      if (acc < bestd || (acc==bestd && k<bestk)){ bestd=acc; bestk=k; }
    }
    if (j==0) out[OFF_SYM + tok0 + t] = (float)bestk;

    float dmn = sqrtf(fmaxf(mns + x2, 0.f));
    float sum = 0.f;
    #pragma unroll
    for (int i=0;i<32;i++){
      float d = sqrtf(fmaxf(a[i] + x2, 0.f));
      a[i] = __expf(dmn - d);
      sum += a[i];
    }
    #pragma unroll
    for (int m=16;m>=1;m>>=1) sum += __shfl_xor(sum, m);
    float rs = 1.f/sum;
    #pragma unroll
    for (int i=0;i<32;i++){
      *(unsigned short*)(srow + ((2*(j+32*i)) ^ tswz)) = f2bf(clamp01(a[i]*rs));
    }
    const float* hrow = centers + (size_t)bestk*CDIM;
    #pragma unroll
    for (int q2=0;q2<8;q2++){
      *(unsigned short*)((char*)H + (size_t)t*512 + ((2*(j+32*q2)) ^ tswz)) = f2bf(hrow[j+32*q2]);
    }
  }
  __syncthreads();

  // ---- P2a: phi fp32 stores (full 128B line per c-row) ----
  #pragma unroll
  for (int it=0; it<16; ++it){
    int e = tid + 512*it;                // 0..8191: c = e>>3, q = e&7
    int c = e>>3, q = e&7;
    float4 v; float* vp = (float*)&v;
    #pragma unroll
    for (int u=0;u<4;u++){
      int t = 4*q + u;
      vp[u] = bf2f(*(const unsigned short*)((const char*)S + (size_t)t*2048 + ((2*c) ^ ((t&15)<<4))));
    }
    *reinterpret_cast<float4*>(sqg + (size_t)bb*1048576 + (size_t)c*1024 + hw0 + 4*q) = v;
  }
  // ---- P2b: zbar/zhard stores ----
  #pragma unroll
  for (int it=0; it<4; ++it){
    int e = tid + 512*it;                // 0..2047: d = e>>3, q = e&7
    int d = e>>3, q = e&7;
    float4 v; float* vp = (float*)&v;
    #pragma unroll
    for (int u=0;u<4;u++){
      int t = 4*q + u;
      vp[u] = bf2f(*(const unsigned short*)((const char*)H + (size_t)t*512 + ((2*d) ^ ((t&15)<<4))));
    }
    size_t base = (size_t)bb*262144 + (size_t)d*1024 + hw0 + 4*q;
    *reinterpret_cast<float4*>(out + OFF_ZBAR  + base) = v;
    *reinterpret_cast<float4*>(out + OFF_ZHARD + base) = v;
  }
  __syncthreads();   // H reads done before zsoft staging overwrites H

  // ---- P3: GEMM2 — zsoft = centers^T @ phi^T; A = ct16 d-rows, B = phi from S rows ----
  {
    f32x4 acc[2][2] = {{{0.f,0.f,0.f,0.f},{0.f,0.f,0.f,0.f}},
                       {{0.f,0.f,0.f,0.f},{0.f,0.f,0.f,0.f}}};
    const unsigned short* ar0 = ct16 + (size_t)(16*w + l15)*CNUM;
    const unsigned short* ar1 = ct16 + (size_t)(16*(w+8) + l15)*CNUM;
    const char* br0 = (const char*)S + (size_t)l15*2048;        // token t' = l15
    const char* br1 = (const char*)S + (size_t)(16+l15)*2048;   // token t' = 16+l15
    const int bswz = l15<<4;   // (t'&15)<<4 is l15<<4 for both rows
    #pragma unroll 8
    for (int s=0;s<32;s++){
      bf16x8 b0 = *reinterpret_cast<const bf16x8*>(br0 + ((64*s + 16*g) ^ bswz));
      bf16x8 b1 = *reinterpret_cast<const bf16x8*>(br1 + ((64*s + 16*g) ^ bswz));
      bf16x8 a0 = *reinterpret_cast<const bf16x8*>(ar0 + 32*s + 8*g);
      bf16x8 a1 = *reinterpret_cast<const bf16x8*>(ar1 + 32*s + 8*g);
      acc[0][0] = __builtin_amdgcn_mfma_f32_16x16x32_bf16(a0, b0, acc[0][0], 0,0,0);
      acc[0][1] = __builtin_amdgcn_mfma_f32_16x16x32_bf16(a0, b1, acc[0][1], 0,0,0);
      acc[1][0] = __builtin_amdgcn_mfma_f32_16x16x32_bf16(a1, b0, acc[1][0], 0,0,0);
      acc[1][1] = __builtin_amdgcn_mfma_f32_16x16x32_bf16(a1, b1, acc[1][1], 0,0,0);
    }
    // stage zsoft bf16 -> H: d = 16*mt + 4g + r, t = nt*16 + l15
    #pragma unroll
    for (int mi=0;mi<2;mi++){
      #pragma unroll
      for (int nt=0;nt<2;nt++){
        f32x4 ac = acc[mi][nt];
        int mt = w + 8*mi;
        int t  = nt*16 + l15;
        int d0 = 16*mt + 4*g;
        u16x4 pk;
        pk[0] = f2bf(ac[0]); pk[1] = f2bf(ac[1]);
        pk[2] = f2bf(ac[2]); pk[3] = f2bf(ac[3]);
        *reinterpret_cast<u16x4*>((char*)H + (size_t)t*512 + ((2*d0) ^ ((t&15)<<4))) = pk;
      }
    }
  }
  __syncthreads();

  // ---- P4: zsoft store ----
  #pragma unroll
  for (int it=0; it<4; ++it){
    int e = tid + 512*it;
    int d = e>>3, q = e&7;
    float4 v; float* vp = (float*)&v;
    #pragma unroll
    for (int u=0;u<4;u++){
      int t = 4*q + u;
      vp[u] = bf2f(*(const unsigned short*)((const char*)H + (size_t)t*512 + ((2*d) ^ ((t&15)<<4))));
    }
    *reinterpret_cast<float4*>(out + OFF_ZSOFT + (size_t)bb*262144 + (size_t)d*1024 + hw0 + 4*q) = v;
  }
}

extern "C" void kernel_launch(void* const* d_in, const int* in_sizes, int n_in,
                              void* d_out, int out_size, void* d_ws, size_t ws_size,
                              hipStream_t stream) {
  const float* data    = (const float*)d_in[0];
  const float* centers = (const float*)d_in[1];
  float* out           = (float*)d_out;

  unsigned short* cb16 = (unsigned short*)d_ws;                         // 512 KB
  unsigned short* ct16 = (unsigned short*)((char*)d_ws + 524288);       // 512 KB
  float*          e2   = (float*)((char*)d_ws + 1048576);               // 4 KB

  prep_convert<<<dim3(256), dim3(256), 0, stream>>>(centers, cb16, ct16);
  prep_e2<<<dim3(4), dim3(256), 0, stream>>>(centers, e2);
  k1_gemm1<<<dim3(1024), dim3(512), 0, stream>>>(data, cb16, e2, out + OFF_PHI);
  k2_all<<<dim3(2048), dim3(512), 0, stream>>>(data, centers, ct16, out);
}